// Round 3
// baseline (1956.295 us; speedup 1.0000x reference)
//
#include <hip/hip_runtime.h>
#include <stdint.h>

typedef unsigned short ushortT;
typedef __attribute__((ext_vector_type(8))) short short8;     // 8 x bf16 (MFMA frag)
typedef __attribute__((ext_vector_type(4))) float float4v;
typedef __attribute__((ext_vector_type(4))) int int4v;
typedef __attribute__((ext_vector_type(2))) int int2v;
typedef __attribute__((ext_vector_type(4))) unsigned short ushort4v;

// ---- workspace layout (bytes) ----
#define OFF_HDR      0            // int[3]: K, maxlen, mask_mode
#define OFF_LEN      8192         // int[256]
#define OFF_CUMM     12288        // int[512]
#define OFF_CUMP     16384        // int[512]
#define OFF_MTI      32768        // int[131072]  maskTrueIdx
#define OFF_PARR     557056       // int[131072]  p_array (packed rank or -1)
#define OFF_WIH      1605632      // bf16[768*256]
#define OFF_WHH      1998848      // bf16[768*256]
#define OFF_GI       2392064      // bf16[131072*768] input projections (packed order)

#define HLAST_OFF    33554432     // floats: T*B*H

__device__ __forceinline__ ushortT f2bf(float f) {
  unsigned u = __float_as_uint(f);
  unsigned r = (u + 0x7fffu + ((u >> 16) & 1u)) >> 16;
  return (ushortT)r;
}
__device__ __forceinline__ float bf2f(ushortT h) {
  return __uint_as_float(((unsigned)h) << 16);
}
__device__ __forceinline__ float sigf(float x) { return 1.f / (1.f + __expf(-x)); }
__device__ __forceinline__ float tanhfast(float x) { return 1.f - 2.f / (1.f + __expf(2.f * x)); }

// ---------------- k_prep: lengths, row/col sums, scans, mask dtype detect ----------------
__global__ __launch_bounds__(512) void k_prep(const int* __restrict__ mask, int* __restrict__ wsi) {
  __shared__ int m_s[512], colp[512], len_s[256], sA[512], sB[512];
  __shared__ int sh_mode;
  const int tid = threadIdx.x;
  if (tid == 0) sh_mode = 0;
  __syncthreads();
  int bad = 0;
  for (int i = tid; i < 32768; i += 512) {
    unsigned v = ((const unsigned*)mask)[i];
    if (v > 1u) bad = 1;
  }
  if (bad) atomicOr(&sh_mode, 1);
  __syncthreads();
  const int mode = sh_mode;

  int s = 0;
  if (mode) {
    const unsigned char* mb = (const unsigned char*)mask;
    for (int c = 0; c < 256; c += 4) {
      unsigned v = *(const unsigned*)(mb + tid * 256 + c);
      s += (v & 0xff) + ((v >> 8) & 0xff) + ((v >> 16) & 0xff) + ((v >> 24) & 0xff);
    }
  } else {
    const int4v* mr = (const int4v*)(mask + tid * 256);
    for (int c = 0; c < 64; ++c) { int4v v = mr[c]; s += v[0] + v[1] + v[2] + v[3]; }
  }
  m_s[tid] = s;

  const int b = tid & 255, hh = tid >> 8;
  int cs = 0;
  if (mode) {
    const unsigned char* mb = (const unsigned char*)mask;
    for (int r = hh * 256; r < hh * 256 + 256; ++r) cs += mb[r * 256 + b];
  } else {
    for (int r = hh * 256; r < hh * 256 + 256; ++r) cs += mask[r * 256 + b];
  }
  colp[tid] = cs;
  __syncthreads();
  if (tid < 256) len_s[tid] = colp[tid] + colp[tid + 256];
  __syncthreads();

  int nt = 0;
  for (int i = 0; i < 256; ++i) nt += (len_s[i] > tid) ? 1 : 0;

  sA[tid] = m_s[tid]; sB[tid] = nt;
  for (int off = 1; off < 512; off <<= 1) {
    __syncthreads();
    int am = (tid >= off) ? sA[tid - off] : 0;
    int an = (tid >= off) ? sB[tid - off] : 0;
    __syncthreads();
    sA[tid] += am; sB[tid] += an;
  }
  __syncthreads();
  wsi[OFF_CUMM / 4 + tid] = sA[tid] - m_s[tid];
  wsi[OFF_CUMP / 4 + tid] = sB[tid] - nt;
  if (tid < 256) wsi[OFF_LEN / 4 + tid] = len_s[tid];

  colp[tid] = (tid < 256) ? len_s[tid] : 0;
  for (int off = 256; off >= 1; off >>= 1) {
    __syncthreads();
    int o = (tid < off) ? colp[tid + off] : 0;
    __syncthreads();
    if (tid < off) colp[tid] = max(colp[tid], o);
  }
  __syncthreads();
  if (tid == 0) { wsi[0] = sA[511]; wsi[1] = colp[0]; wsi[2] = mode; }
}

// ---------------- k_build: per-row scans -> maskTrueIdx and p_array ----------------
__global__ __launch_bounds__(256) void k_build(const int* __restrict__ mask, int* __restrict__ wsi) {
  const int t = blockIdx.x, b = threadIdx.x;
  const int mode = wsi[2];
  const int lane = b & 63, wv = b >> 6;
  int mflag = mode ? (int)((const unsigned char*)mask)[t * 256 + b] : mask[t * 256 + b];
  mflag = mflag ? 1 : 0;
  const int len = wsi[OFF_LEN / 4 + b];
  const int pflag = (t < len) ? 1 : 0;
  unsigned long long bm = __ballot(mflag), bp = __ballot(pflag);
  __shared__ int wm[4], wp[4];
  if (lane == 0) { wm[wv] = __popcll(bm); wp[wv] = __popcll(bp); }
  __syncthreads();
  int baseM = 0, baseP = 0;
  for (int i = 0; i < wv; ++i) { baseM += wm[i]; baseP += wp[i]; }
  unsigned long long lt = (1ull << lane) - 1ull;
  const int moff = baseM + __popcll(bm & lt);
  const int poff = baseP + __popcll(bp & lt);
  const int j = t * 256 + b;
  if (mflag) wsi[OFF_MTI / 4 + wsi[OFF_CUMM / 4 + t] + moff] = j;
  wsi[OFF_PARR / 4 + j] = pflag ? (wsi[OFF_CUMP / 4 + t] + poff) : -1;
}

// ---------------- k_wcvt: W_ih, W_hh fp32 -> bf16 ----------------
__global__ __launch_bounds__(256) void k_wcvt(const float* __restrict__ Wih,
                                              const float* __restrict__ Whh,
                                              int* __restrict__ wsi) {
  const int idx = (blockIdx.x * 256 + threadIdx.x) * 4;
  const float* src;
  ushortT* dst;
  if (idx < 196608) { src = Wih + idx; dst = (ushortT*)((char*)wsi + OFF_WIH) + idx; }
  else { src = Whh + (idx - 196608); dst = (ushortT*)((char*)wsi + OFF_WHH) + (idx - 196608); }
  float4v v = *(const float4v*)src;
  ushort4v o;
  o[0] = f2bf(v[0]); o[1] = f2bf(v[1]); o[2] = f2bf(v[2]); o[3] = f2bf(v[3]);
  *(ushort4v*)dst = o;
}

// ---------------- k_gemm: gi[p] = bf16( x[mti[p]] @ W_ih^T + b_ih )  (gather + bias fused) ----
__global__ __launch_bounds__(256, 2) void k_gemm(const float* __restrict__ x,
                                                 const float* __restrict__ bih,
                                                 int* __restrict__ wsi) {
  const int K = wsi[0];
  const int m0 = blockIdx.x * 128;
  if (m0 >= K) return;
  const int n0 = blockIdx.y * 128;
  char* wsc = (char*)wsi;
  const ushortT* Bw = (const ushortT*)(wsc + OFF_WIH);
  ushortT* C = (ushortT*)(wsc + OFF_GI);
  __shared__ ushortT As[128 * 72], Bs[128 * 72];
  __shared__ int mti_s[128];
  const int tid = threadIdx.x, w = tid >> 6, lane = tid & 63;
  const int l15 = lane & 15, quad = lane >> 4;
  if (tid < 128) {
    int m = m0 + tid;
    mti_s[tid] = (m < K) ? wsi[OFF_MTI / 4 + m] : 0;
  }
  float biasj[4];
#pragma unroll
  for (int j = 0; j < 4; ++j) biasj[j] = bih[n0 + (w & 1) * 64 + j * 16 + l15];
  float4v acc[4][4];
#pragma unroll
  for (int i = 0; i < 4; ++i)
#pragma unroll
    for (int j = 0; j < 4; ++j) acc[i][j] = (float4v){0.f, 0.f, 0.f, 0.f};

  for (int k0 = 0; k0 < 256; k0 += 64) {
    __syncthreads();
#pragma unroll
    for (int i = 0; i < 8; ++i) {          // A: gather 128 rows x 64 k (fp32 -> bf16)
      int cid = i * 256 + tid;
      int row = cid >> 4, c4 = cid & 15;
      float4v v = *(const float4v*)(x + (size_t)mti_s[row] * 256 + k0 + c4 * 4);
      ushort4v o;
      o[0] = f2bf(v[0]); o[1] = f2bf(v[1]); o[2] = f2bf(v[2]); o[3] = f2bf(v[3]);
      *(ushort4v*)(As + row * 72 + c4 * 4) = o;
    }
#pragma unroll
    for (int i = 0; i < 4; ++i) {          // B: W_ih bf16
      int cid = i * 256 + tid;
      int row = cid >> 3, c8 = cid & 7;
      int4v vb = *(const int4v*)(Bw + (size_t)(n0 + row) * 256 + k0 + c8 * 8);
      *(int4v*)(Bs + row * 72 + c8 * 8) = vb;
    }
    __syncthreads();
#pragma unroll
    for (int kk = 0; kk < 2; ++kk) {
      short8 af[4], bfr[4];
#pragma unroll
      for (int i = 0; i < 4; ++i)
        af[i] = *(const short8*)(As + ((w >> 1) * 64 + i * 16 + l15) * 72 + kk * 32 + quad * 8);
#pragma unroll
      for (int j = 0; j < 4; ++j)
        bfr[j] = *(const short8*)(Bs + ((w & 1) * 64 + j * 16 + l15) * 72 + kk * 32 + quad * 8);
#pragma unroll
      for (int i = 0; i < 4; ++i)
#pragma unroll
        for (int j = 0; j < 4; ++j)
          acc[i][j] = __builtin_amdgcn_mfma_f32_16x16x32_bf16(af[i], bfr[j], acc[i][j], 0, 0, 0);
    }
  }
#pragma unroll
  for (int i = 0; i < 4; ++i) {
    int m = m0 + (w >> 1) * 64 + i * 16 + quad * 4;
#pragma unroll
    for (int j = 0; j < 4; ++j) {
      int n = n0 + (w & 1) * 64 + j * 16 + l15;
#pragma unroll
      for (int r = 0; r < 4; ++r)
        if (m + r < K) C[(size_t)(m + r) * 768 + n] = f2bf(acc[i][j][r] + biasj[j]);
    }
  }
}

// ---------------- k_rec: GRU recurrence, operand-swapped MFMA (A = W_hh, B = h) -------------
// 16 blocks x 512 threads (8 waves, 2/SIMD). Wave w owns h-columns [32w, 32w+32): the r,z,n
// gate-row tiles for those columns. MFMA output lands with col=batch(l15), row=gate-row
// (quad*4+r), so each lane holds gh_r/gh_z/gh_n for ITS OWN (batch, col) pairs -> gates run
// fully in registers. No gh LDS round-trip; ONE barrier/step (h double-buffered in LDS).
// W_hh (192 regs worth) is NOT held resident (it can't fit under the 256-reg cap -> the old
// version spilled); it is streamed from XCD-L2 every step through a 2x(6-tile,2-kk) register
// pipeline (96 regs) whose next-step chunks are issued under the gates phase.
// gi / parr / mti are prefetched 2 steps ahead. b_ih folded into gi (k_gemm); b_hh folded
// into the MFMA accumulator init.
__device__ __forceinline__ void wload6x2(short8* buf, const ushortT* __restrict__ Whh,
                                         int w, int l15, int quad, int kb) {
#pragma unroll
  for (int tt = 0; tt < 6; ++tt) {
    const int row = (tt >> 1) * 256 + 32 * w + (tt & 1) * 16 + l15;
#pragma unroll
    for (int q = 0; q < 2; ++q)
      buf[tt * 2 + q] = *(const short8*)(Whh + (size_t)row * 256 + (kb + q) * 32 + quad * 8);
  }
}

__device__ __forceinline__ void chunk_mfma(float4v* acc, const short8* buf,
                                           const ushortT* __restrict__ hc,
                                           int l15, int quad, int kb) {
  short8 hf0 = *(const short8*)(hc + l15 * 264 + kb * 32 + quad * 8);
  short8 hf1 = *(const short8*)(hc + l15 * 264 + (kb + 1) * 32 + quad * 8);
#pragma unroll
  for (int tt = 0; tt < 6; ++tt) {
    acc[tt] = __builtin_amdgcn_mfma_f32_16x16x32_bf16(buf[tt * 2], hf0, acc[tt], 0, 0, 0);
    acc[tt] = __builtin_amdgcn_mfma_f32_16x16x32_bf16(buf[tt * 2 + 1], hf1, acc[tt], 0, 0, 0);
  }
}

__device__ __forceinline__ void giload(int2v* R, int2v* Z, int2v* N,
                                       const ushortT* __restrict__ gib, int p, int w, int quad) {
  const size_t pb = (size_t)max(p, 0) * 768 + 32 * w + quad * 4;
#pragma unroll
  for (int hh = 0; hh < 2; ++hh) {
    R[hh] = *(const int2v*)(gib + pb + hh * 16);
    Z[hh] = *(const int2v*)(gib + pb + 256 + hh * 16);
    N[hh] = *(const int2v*)(gib + pb + 512 + hh * 16);
  }
}

__global__ __launch_bounds__(512, 2) void k_rec(const float* __restrict__ bhh,
                                                const float* __restrict__ h0,
                                                int* __restrict__ wsi,
                                                float* __restrict__ out) {
  const int b0 = blockIdx.x * 16;
  const int tid = threadIdx.x;
  const int w = tid >> 6, lane = tid & 63, l15 = lane & 15, quad = lane >> 4;
  char* wsc = (char*)wsi;
  const ushortT* Whh = (const ushortT*)(wsc + OFF_WHH);
  const ushortT* gib = (const ushortT*)(wsc + OFF_GI);
  const int* parr = wsi + OFF_PARR / 4;
  const int* mti = wsi + OFF_MTI / 4;
  const int K = wsi[0];
  const int bg = b0 + l15;                 // this lane's batch
  const int cbase = 32 * w + quad * 4;     // first h-column of run hh=0 (hh=1 adds +16)

  __shared__ ushortT hbf[2][16 * 264];     // double-buffered h, bf16, stride 264

  // block tmax = max length over the 16 batches (same in all waves)
  int tmax = wsi[OFF_LEN / 4 + bg];
#pragma unroll
  for (int o = 1; o < 16; o <<= 1) tmax = max(tmax, __shfl_xor(tmax, o));

  // b_hh folded into accumulator init: bI[g*2+hh][r] = bhh[g*256 + cbase + hh*16 + r]
  float4v bI[6];
#pragma unroll
  for (int g = 0; g < 3; ++g)
#pragma unroll
    for (int hh = 0; hh < 2; ++hh)
      bI[g * 2 + hh] = *(const float4v*)(bhh + g * 256 + cbase + hh * 16);

  // h0 -> hreg (f32, persistent) + hbf[0] (bf16)
  float hreg[8];
  {
    float4v a = *(const float4v*)(h0 + (size_t)bg * 256 + cbase);
    float4v b = *(const float4v*)(h0 + (size_t)bg * 256 + cbase + 16);
    ushort4v pa, pb;
#pragma unroll
    for (int r = 0; r < 4; ++r) {
      hreg[r] = a[r]; hreg[4 + r] = b[r];
      pa[r] = f2bf(a[r]); pb[r] = f2bf(b[r]);
    }
    *(ushort4v*)(&hbf[0][l15 * 264 + cbase]) = pa;
    *(ushort4v*)(&hbf[0][l15 * 264 + cbase + 16]) = pb;
  }

  // W stream prologue: chunks kk{0,1} and kk{2,3}
  short8 wa[12], wb[12];
  wload6x2(wa, Whh, w, l15, quad, 0);
  wload6x2(wb, Whh, w, l15, quad, 2);

  // gi / parr / mti prologue (t = 0, 1)
  int p0 = parr[bg], p1 = parr[256 + bg];
  int m0 = mti[bg], m1 = mti[256 + bg];
  int2v g0R[2], g0Z[2], g0N[2], g1R[2], g1Z[2], g1N[2];
  giload(g0R, g0Z, g0N, gib, p0, w, quad);
  giload(g1R, g1Z, g1N, gib, p1, w, quad);

  __syncthreads();

  for (int t = 0; t < tmax; ++t) {
    const ushortT* hc = hbf[t & 1];
    ushortT* hn = hbf[(t + 1) & 1];

    // prefetch step t+2 metadata (used at the bottom of this step)
    int p2 = -1, m2 = 0;
    if (t + 2 < 512) {
      p2 = parr[(t + 2) * 256 + bg];
      m2 = mti[(t + 2) * 256 + bg];
    }

    // [A] gh = W_hh @ h^T (+ bhh via init), streamed-W pipeline
    float4v acc[6];
#pragma unroll
    for (int i = 0; i < 6; ++i) acc[i] = bI[i];

    chunk_mfma(acc, wa, hc, l15, quad, 0);
    wload6x2(wa, Whh, w, l15, quad, 4);
    chunk_mfma(acc, wb, hc, l15, quad, 2);
    wload6x2(wb, Whh, w, l15, quad, 6);
    chunk_mfma(acc, wa, hc, l15, quad, 4);
    wload6x2(wa, Whh, w, l15, quad, 0);     // next-step chunk0 (lands under gates)
    chunk_mfma(acc, wb, hc, l15, quad, 6);
    wload6x2(wb, Whh, w, l15, quad, 2);     // next-step chunk1

    // [B] gates, fully in registers
    const bool valid = (p0 >= 0);
#pragma unroll
    for (int hh = 0; hh < 2; ++hh)
#pragma unroll
      for (int r = 0; r < 4; ++r) {
        float gir = bf2f((ushortT)(((unsigned)g0R[hh][r >> 1]) >> ((r & 1) * 16)));
        float giz = bf2f((ushortT)(((unsigned)g0Z[hh][r >> 1]) >> ((r & 1) * 16)));
        float gin = bf2f((ushortT)(((unsigned)g0N[hh][r >> 1]) >> ((r & 1) * 16)));
        float rr = sigf(gir + acc[hh][r]);           // acc[0*2+hh] = r-gate (has bhh)
        float zz = sigf(giz + acc[2 + hh][r]);       // z-gate
        float nn = tanhfast(gin + rr * acc[4 + hh][r]);  // n-gate; gin has bih_n, acc has bhh_n
        float hv = nn + zz * (hreg[hh * 4 + r] - nn);
        hreg[hh * 4 + r] = valid ? hv : hreg[hh * 4 + r];
      }

    // scores scatter (packed row t*256+bg -> masked position mti[...])
    const int nflat = t * 256 + bg;
    if (valid && nflat < K) {
      float4v o0 = {hreg[0], hreg[1], hreg[2], hreg[3]};
      float4v o1 = {hreg[4], hreg[5], hreg[6], hreg[7]};
      *(float4v*)(out + (size_t)m0 * 256 + cbase) = o0;
      *(float4v*)(out + (size_t)m0 * 256 + cbase + 16) = o1;
    }

    // h -> next LDS buffer (always: buffer is stale)
    {
      ushort4v q0, q1;
#pragma unroll
      for (int r = 0; r < 4; ++r) { q0[r] = f2bf(hreg[r]); q1[r] = f2bf(hreg[4 + r]); }
      *(ushort4v*)(hn + l15 * 264 + cbase) = q0;
      *(ushort4v*)(hn + l15 * 264 + cbase + 16) = q1;
    }

    // rotate gi pipeline and issue t+2 loads (covered by next step's MFMA phase)
#pragma unroll
    for (int hh = 0; hh < 2; ++hh) { g0R[hh] = g1R[hh]; g0Z[hh] = g1Z[hh]; g0N[hh] = g1N[hh]; }
    giload(g1R, g1Z, g1N, gib, p2, w, quad);
    p0 = p1; p1 = p2; m0 = m1; m1 = m2;
    __syncthreads();
  }

  // h_last
  {
    float4v o0 = {hreg[0], hreg[1], hreg[2], hreg[3]};
    float4v o1 = {hreg[4], hreg[5], hreg[6], hreg[7]};
    *(float4v*)(out + HLAST_OFF + (size_t)bg * 256 + cbase) = o0;
    *(float4v*)(out + HLAST_OFF + (size_t)bg * 256 + cbase + 16) = o1;
  }
}

extern "C" void kernel_launch(void* const* d_in, const int* in_sizes, int n_in,
                              void* d_out, int out_size, void* d_ws, size_t ws_size,
                              hipStream_t stream) {
  const float* x = (const float*)d_in[0];
  const float* h0 = (const float*)d_in[1];
  const int* mask = (const int*)d_in[2];
  const float* Wih = (const float*)d_in[3];
  const float* Whh = (const float*)d_in[4];
  const float* bih = (const float*)d_in[5];
  const float* bhh = (const float*)d_in[6];
  float* out = (float*)d_out;
  int* wsi = (int*)d_ws;

  hipMemsetAsync(d_out, 0, (size_t)out_size * 4, stream);  // unmasked / padded positions emit 0

  k_prep<<<1, 512, 0, stream>>>(mask, wsi);
  k_build<<<512, 256, 0, stream>>>(mask, wsi);
  k_wcvt<<<384, 256, 0, stream>>>(Wih, Whh, wsi);
  k_gemm<<<dim3(1024, 6), 256, 0, stream>>>(x, bih, wsi);
  k_rec<<<16, 512, 0, stream>>>(bhh, h0, wsi, out);
}

// Round 4
// 1929.328 us; speedup vs baseline: 1.0140x; 1.0140x over previous
//
#include <hip/hip_runtime.h>
#include <stdint.h>

typedef unsigned short ushortT;
typedef __attribute__((ext_vector_type(8))) short short8;     // 8 x bf16 (MFMA frag)
typedef __attribute__((ext_vector_type(4))) float float4v;
typedef __attribute__((ext_vector_type(4))) int int4v;
typedef __attribute__((ext_vector_type(2))) int int2v;
typedef __attribute__((ext_vector_type(4))) unsigned short ushort4v;

// ---- workspace layout (bytes) ----
#define OFF_HDR      0            // int[3]: K, maxlen, mask_mode
#define OFF_LEN      8192         // int[256]
#define OFF_CUMM     12288        // int[512]
#define OFF_CUMP     16384        // int[512]
#define OFF_MTI      32768        // int[131072]  maskTrueIdx
#define OFF_PARR     557056       // int[131072]  p_array (packed rank or -1)
#define OFF_WIH      1605632      // bf16[768*256]
#define OFF_WHH      1998848      // bf16[768*256]
#define OFF_GI       2392064      // bf16[131072*768] input projections (packed order)

#define HLAST_OFF    33554432     // floats: T*B*H

__device__ __forceinline__ ushortT f2bf(float f) {
  unsigned u = __float_as_uint(f);
  unsigned r = (u + 0x7fffu + ((u >> 16) & 1u)) >> 16;
  return (ushortT)r;
}
__device__ __forceinline__ float bf2f(ushortT h) {
  return __uint_as_float(((unsigned)h) << 16);
}
__device__ __forceinline__ float sigf(float x) { return 1.f / (1.f + __expf(-x)); }
__device__ __forceinline__ float tanhfast(float x) { return 1.f - 2.f / (1.f + __expf(2.f * x)); }

// ---------------- k_prep: lengths, row/col sums, scans, mask dtype detect ----------------
__global__ __launch_bounds__(512) void k_prep(const int* __restrict__ mask, int* __restrict__ wsi) {
  __shared__ int m_s[512], colp[512], len_s[256], sA[512], sB[512];
  __shared__ int sh_mode;
  const int tid = threadIdx.x;
  if (tid == 0) sh_mode = 0;
  __syncthreads();
  int bad = 0;
  for (int i = tid; i < 32768; i += 512) {
    unsigned v = ((const unsigned*)mask)[i];
    if (v > 1u) bad = 1;
  }
  if (bad) atomicOr(&sh_mode, 1);
  __syncthreads();
  const int mode = sh_mode;

  int s = 0;
  if (mode) {
    const unsigned char* mb = (const unsigned char*)mask;
    for (int c = 0; c < 256; c += 4) {
      unsigned v = *(const unsigned*)(mb + tid * 256 + c);
      s += (v & 0xff) + ((v >> 8) & 0xff) + ((v >> 16) & 0xff) + ((v >> 24) & 0xff);
    }
  } else {
    const int4v* mr = (const int4v*)(mask + tid * 256);
    for (int c = 0; c < 64; ++c) { int4v v = mr[c]; s += v[0] + v[1] + v[2] + v[3]; }
  }
  m_s[tid] = s;

  const int b = tid & 255, hh = tid >> 8;
  int cs = 0;
  if (mode) {
    const unsigned char* mb = (const unsigned char*)mask;
    for (int r = hh * 256; r < hh * 256 + 256; ++r) cs += mb[r * 256 + b];
  } else {
    for (int r = hh * 256; r < hh * 256 + 256; ++r) cs += mask[r * 256 + b];
  }
  colp[tid] = cs;
  __syncthreads();
  if (tid < 256) len_s[tid] = colp[tid] + colp[tid + 256];
  __syncthreads();

  int nt = 0;
  for (int i = 0; i < 256; ++i) nt += (len_s[i] > tid) ? 1 : 0;

  sA[tid] = m_s[tid]; sB[tid] = nt;
  for (int off = 1; off < 512; off <<= 1) {
    __syncthreads();
    int am = (tid >= off) ? sA[tid - off] : 0;
    int an = (tid >= off) ? sB[tid - off] : 0;
    __syncthreads();
    sA[tid] += am; sB[tid] += an;
  }
  __syncthreads();
  wsi[OFF_CUMM / 4 + tid] = sA[tid] - m_s[tid];
  wsi[OFF_CUMP / 4 + tid] = sB[tid] - nt;
  if (tid < 256) wsi[OFF_LEN / 4 + tid] = len_s[tid];

  colp[tid] = (tid < 256) ? len_s[tid] : 0;
  for (int off = 256; off >= 1; off >>= 1) {
    __syncthreads();
    int o = (tid < off) ? colp[tid + off] : 0;
    __syncthreads();
    if (tid < off) colp[tid] = max(colp[tid], o);
  }
  __syncthreads();
  if (tid == 0) { wsi[0] = sA[511]; wsi[1] = colp[0]; wsi[2] = mode; }
}

// ---------------- k_build: per-row scans -> maskTrueIdx and p_array ----------------
__global__ __launch_bounds__(256) void k_build(const int* __restrict__ mask, int* __restrict__ wsi) {
  const int t = blockIdx.x, b = threadIdx.x;
  const int mode = wsi[2];
  const int lane = b & 63, wv = b >> 6;
  int mflag = mode ? (int)((const unsigned char*)mask)[t * 256 + b] : mask[t * 256 + b];
  mflag = mflag ? 1 : 0;
  const int len = wsi[OFF_LEN / 4 + b];
  const int pflag = (t < len) ? 1 : 0;
  unsigned long long bm = __ballot(mflag), bp = __ballot(pflag);
  __shared__ int wm[4], wp[4];
  if (lane == 0) { wm[wv] = __popcll(bm); wp[wv] = __popcll(bp); }
  __syncthreads();
  int baseM = 0, baseP = 0;
  for (int i = 0; i < wv; ++i) { baseM += wm[i]; baseP += wp[i]; }
  unsigned long long lt = (1ull << lane) - 1ull;
  const int moff = baseM + __popcll(bm & lt);
  const int poff = baseP + __popcll(bp & lt);
  const int j = t * 256 + b;
  if (mflag) wsi[OFF_MTI / 4 + wsi[OFF_CUMM / 4 + t] + moff] = j;
  wsi[OFF_PARR / 4 + j] = pflag ? (wsi[OFF_CUMP / 4 + t] + poff) : -1;
}

// ---------------- k_wcvt: W_ih, W_hh fp32 -> bf16 ----------------
__global__ __launch_bounds__(256) void k_wcvt(const float* __restrict__ Wih,
                                              const float* __restrict__ Whh,
                                              int* __restrict__ wsi) {
  const int idx = (blockIdx.x * 256 + threadIdx.x) * 4;
  const float* src;
  ushortT* dst;
  if (idx < 196608) { src = Wih + idx; dst = (ushortT*)((char*)wsi + OFF_WIH) + idx; }
  else { src = Whh + (idx - 196608); dst = (ushortT*)((char*)wsi + OFF_WHH) + (idx - 196608); }
  float4v v = *(const float4v*)src;
  ushort4v o;
  o[0] = f2bf(v[0]); o[1] = f2bf(v[1]); o[2] = f2bf(v[2]); o[3] = f2bf(v[3]);
  *(ushort4v*)dst = o;
}

// ---------------- k_gemm: gi[p] = bf16( x[mti[p]] @ W_ih^T + b_ih )  (gather + bias fused) ----
__global__ __launch_bounds__(256, 2) void k_gemm(const float* __restrict__ x,
                                                 const float* __restrict__ bih,
                                                 int* __restrict__ wsi) {
  const int K = wsi[0];
  const int m0 = blockIdx.x * 128;
  if (m0 >= K) return;
  const int n0 = blockIdx.y * 128;
  char* wsc = (char*)wsi;
  const ushortT* Bw = (const ushortT*)(wsc + OFF_WIH);
  ushortT* C = (ushortT*)(wsc + OFF_GI);
  __shared__ ushortT As[128 * 72], Bs[128 * 72];
  __shared__ int mti_s[128];
  const int tid = threadIdx.x, w = tid >> 6, lane = tid & 63;
  const int l15 = lane & 15, quad = lane >> 4;
  if (tid < 128) {
    int m = m0 + tid;
    mti_s[tid] = (m < K) ? wsi[OFF_MTI / 4 + m] : 0;
  }
  float biasj[4];
#pragma unroll
  for (int j = 0; j < 4; ++j) biasj[j] = bih[n0 + (w & 1) * 64 + j * 16 + l15];
  float4v acc[4][4];
#pragma unroll
  for (int i = 0; i < 4; ++i)
#pragma unroll
    for (int j = 0; j < 4; ++j) acc[i][j] = (float4v){0.f, 0.f, 0.f, 0.f};

  for (int k0 = 0; k0 < 256; k0 += 64) {
    __syncthreads();
#pragma unroll
    for (int i = 0; i < 8; ++i) {          // A: gather 128 rows x 64 k (fp32 -> bf16)
      int cid = i * 256 + tid;
      int row = cid >> 4, c4 = cid & 15;
      float4v v = *(const float4v*)(x + (size_t)mti_s[row] * 256 + k0 + c4 * 4);
      ushort4v o;
      o[0] = f2bf(v[0]); o[1] = f2bf(v[1]); o[2] = f2bf(v[2]); o[3] = f2bf(v[3]);
      *(ushort4v*)(As + row * 72 + c4 * 4) = o;
    }
#pragma unroll
    for (int i = 0; i < 4; ++i) {          // B: W_ih bf16
      int cid = i * 256 + tid;
      int row = cid >> 3, c8 = cid & 7;
      int4v vb = *(const int4v*)(Bw + (size_t)(n0 + row) * 256 + k0 + c8 * 8);
      *(int4v*)(Bs + row * 72 + c8 * 8) = vb;
    }
    __syncthreads();
#pragma unroll
    for (int kk = 0; kk < 2; ++kk) {
      short8 af[4], bfr[4];
#pragma unroll
      for (int i = 0; i < 4; ++i)
        af[i] = *(const short8*)(As + ((w >> 1) * 64 + i * 16 + l15) * 72 + kk * 32 + quad * 8);
#pragma unroll
      for (int j = 0; j < 4; ++j)
        bfr[j] = *(const short8*)(Bs + ((w & 1) * 64 + j * 16 + l15) * 72 + kk * 32 + quad * 8);
#pragma unroll
      for (int i = 0; i < 4; ++i)
#pragma unroll
        for (int j = 0; j < 4; ++j)
          acc[i][j] = __builtin_amdgcn_mfma_f32_16x16x32_bf16(af[i], bfr[j], acc[i][j], 0, 0, 0);
    }
  }
#pragma unroll
  for (int i = 0; i < 4; ++i) {
    int m = m0 + (w >> 1) * 64 + i * 16 + quad * 4;
#pragma unroll
    for (int j = 0; j < 4; ++j) {
      int n = n0 + (w & 1) * 64 + j * 16 + l15;
#pragma unroll
      for (int r = 0; r < 4; ++r)
        if (m + r < K) C[(size_t)(m + r) * 768 + n] = f2bf(acc[i][j][r] + biasj[j]);
    }
  }
}

// ---------------- k_rec: GRU recurrence, operand-swapped MFMA (A = W_hh, B = h) -------------
// 16 blocks x 512 threads (8 waves, 2/SIMD). Wave w owns h-columns [32w, 32w+32). In-register
// gates (no gh LDS round-trip); W_hh streamed from XCD-L2 each step through a 2-buffer
// register pipeline; gi prefetch distance 1, metadata distance 2.
//
// CRITICAL (round-3 post-mortem): __syncthreads() compiles to `s_waitcnt vmcnt(0)` + barrier,
// draining EVERY in-flight prefetch (W chunks, gi, meta, out-store acks) once per timestep —
// the cross-step pipeline never engaged (14.2k cy/step measured). The per-step sync is now a
// raw s_barrier with lgkmcnt(0)-only drain (h LDS writes visible); VMEM loads stay in flight
// across the step boundary and the compiler's own counted vmcnt dependency-waits cover use.
// All in-flight loads target read-only regions (WHH/GI/PARR/MTI); stores are never re-read.
__device__ __forceinline__ void wload6x2(short8* buf, const ushortT* __restrict__ Whh,
                                         int w, int l15, int quad, int kb) {
#pragma unroll
  for (int tt = 0; tt < 6; ++tt) {
    const int row = (tt >> 1) * 256 + 32 * w + (tt & 1) * 16 + l15;
#pragma unroll
    for (int q = 0; q < 2; ++q)
      buf[tt * 2 + q] = *(const short8*)(Whh + (size_t)row * 256 + (kb + q) * 32 + quad * 8);
  }
}

__device__ __forceinline__ void chunk_mfma(float4v* acc, const short8* buf,
                                           const ushortT* __restrict__ hc,
                                           int l15, int quad, int kb) {
  short8 hf0 = *(const short8*)(hc + l15 * 264 + kb * 32 + quad * 8);
  short8 hf1 = *(const short8*)(hc + l15 * 264 + (kb + 1) * 32 + quad * 8);
#pragma unroll
  for (int tt = 0; tt < 6; ++tt) {
    acc[tt] = __builtin_amdgcn_mfma_f32_16x16x32_bf16(buf[tt * 2], hf0, acc[tt], 0, 0, 0);
    acc[tt] = __builtin_amdgcn_mfma_f32_16x16x32_bf16(buf[tt * 2 + 1], hf1, acc[tt], 0, 0, 0);
  }
}

__device__ __forceinline__ void giload(int2v* R, int2v* Z, int2v* N,
                                       const ushortT* __restrict__ gib, int p, int w, int quad) {
  const size_t pb = (size_t)max(p, 0) * 768 + 32 * w + quad * 4;
#pragma unroll
  for (int hh = 0; hh < 2; ++hh) {
    R[hh] = *(const int2v*)(gib + pb + hh * 16);
    Z[hh] = *(const int2v*)(gib + pb + 256 + hh * 16);
    N[hh] = *(const int2v*)(gib + pb + 512 + hh * 16);
  }
}

__global__ __launch_bounds__(512, 2) void k_rec(const float* __restrict__ bhh,
                                                const float* __restrict__ h0,
                                                int* __restrict__ wsi,
                                                float* __restrict__ out) {
  const int b0 = blockIdx.x * 16;
  const int tid = threadIdx.x;
  const int w = tid >> 6, lane = tid & 63, l15 = lane & 15, quad = lane >> 4;
  char* wsc = (char*)wsi;
  const ushortT* Whh = (const ushortT*)(wsc + OFF_WHH);
  const ushortT* gib = (const ushortT*)(wsc + OFF_GI);
  const int* parr = wsi + OFF_PARR / 4;
  const int* mti = wsi + OFF_MTI / 4;
  const int K = wsi[0];
  const int bg = b0 + l15;                 // this lane's batch
  const int cbase = 32 * w + quad * 4;     // first h-column of run hh=0 (hh=1 adds +16)

  __shared__ ushortT hbf[2][16 * 264];     // double-buffered h, bf16, stride 264

  // block tmax = max length over the 16 batches (same in all waves)
  int tmax = wsi[OFF_LEN / 4 + bg];
#pragma unroll
  for (int o = 1; o < 16; o <<= 1) tmax = max(tmax, __shfl_xor(tmax, o));

  // b_hh folded into accumulator init: bI[g*2+hh][r] = bhh[g*256 + cbase + hh*16 + r]
  float4v bI[6];
#pragma unroll
  for (int g = 0; g < 3; ++g)
#pragma unroll
    for (int hh = 0; hh < 2; ++hh)
      bI[g * 2 + hh] = *(const float4v*)(bhh + g * 256 + cbase + hh * 16);

  // h0 -> hreg (f32, persistent) + hbf[0] (bf16)
  float hreg[8];
  {
    float4v a = *(const float4v*)(h0 + (size_t)bg * 256 + cbase);
    float4v b = *(const float4v*)(h0 + (size_t)bg * 256 + cbase + 16);
    ushort4v pa, pb;
#pragma unroll
    for (int r = 0; r < 4; ++r) {
      hreg[r] = a[r]; hreg[4 + r] = b[r];
      pa[r] = f2bf(a[r]); pb[r] = f2bf(b[r]);
    }
    *(ushort4v*)(&hbf[0][l15 * 264 + cbase]) = pa;
    *(ushort4v*)(&hbf[0][l15 * 264 + cbase + 16]) = pb;
  }

  // W stream prologue: chunks kk{0,1} and kk{2,3}
  short8 wa[12], wb[12];
  wload6x2(wa, Whh, w, l15, quad, 0);
  wload6x2(wb, Whh, w, l15, quad, 2);

  // gi / parr / mti prologue (t = 0, 1)
  int p0 = parr[bg], p1 = parr[256 + bg];
  int m0 = mti[bg], m1 = mti[256 + bg];
  int2v g0R[2], g0Z[2], g0N[2], g1R[2], g1Z[2], g1N[2];
  giload(g0R, g0Z, g0N, gib, p0, w, quad);
  giload(g1R, g1Z, g1N, gib, p1, w, quad);

  __syncthreads();

  for (int t = 0; t < tmax; ++t) {
    const ushortT* hc = hbf[t & 1];
    ushortT* hn = hbf[(t + 1) & 1];

    // prefetch step t+2 metadata (used at the bottom of this step)
    int p2 = -1, m2 = 0;
    if (t + 2 < 512) {
      p2 = parr[(t + 2) * 256 + bg];
      m2 = mti[(t + 2) * 256 + bg];
    }

    // [A] gh = W_hh @ h^T (+ bhh via init), streamed-W pipeline
    float4v acc[6];
#pragma unroll
    for (int i = 0; i < 6; ++i) acc[i] = bI[i];

    chunk_mfma(acc, wa, hc, l15, quad, 0);
    wload6x2(wa, Whh, w, l15, quad, 4);
    chunk_mfma(acc, wb, hc, l15, quad, 2);
    wload6x2(wb, Whh, w, l15, quad, 6);
    chunk_mfma(acc, wa, hc, l15, quad, 4);
    wload6x2(wa, Whh, w, l15, quad, 0);     // next-step chunk0 (stays in flight across barrier)
    chunk_mfma(acc, wb, hc, l15, quad, 6);
    wload6x2(wb, Whh, w, l15, quad, 2);     // next-step chunk1

    // [B] gates, fully in registers
    const bool valid = (p0 >= 0);
#pragma unroll
    for (int hh = 0; hh < 2; ++hh)
#pragma unroll
      for (int r = 0; r < 4; ++r) {
        float gir = bf2f((ushortT)(((unsigned)g0R[hh][r >> 1]) >> ((r & 1) * 16)));
        float giz = bf2f((ushortT)(((unsigned)g0Z[hh][r >> 1]) >> ((r & 1) * 16)));
        float gin = bf2f((ushortT)(((unsigned)g0N[hh][r >> 1]) >> ((r & 1) * 16)));
        float rr = sigf(gir + acc[hh][r]);           // acc[0*2+hh] = r-gate (has bhh)
        float zz = sigf(giz + acc[2 + hh][r]);       // z-gate
        float nn = tanhfast(gin + rr * acc[4 + hh][r]);  // n-gate; gin has bih_n, acc has bhh_n
        float hv = nn + zz * (hreg[hh * 4 + r] - nn);
        hreg[hh * 4 + r] = valid ? hv : hreg[hh * 4 + r];
      }

    // scores scatter (packed row t*256+bg -> masked position mti[...])
    const int nflat = t * 256 + bg;
    if (valid && nflat < K) {
      float4v o0 = {hreg[0], hreg[1], hreg[2], hreg[3]};
      float4v o1 = {hreg[4], hreg[5], hreg[6], hreg[7]};
      *(float4v*)(out + (size_t)m0 * 256 + cbase) = o0;
      *(float4v*)(out + (size_t)m0 * 256 + cbase + 16) = o1;
    }

    // rotate gi pipeline and issue t+1-use loads early (stay in flight across barrier)
#pragma unroll
    for (int hh = 0; hh < 2; ++hh) { g0R[hh] = g1R[hh]; g0Z[hh] = g1Z[hh]; g0N[hh] = g1N[hh]; }
    giload(g1R, g1Z, g1N, gib, p2, w, quad);
    p0 = p1; p1 = p2; m0 = m1; m1 = m2;

    // h -> next LDS buffer (always: buffer is stale)
    {
      ushort4v q0, q1;
#pragma unroll
      for (int r = 0; r < 4; ++r) { q0[r] = f2bf(hreg[r]); q1[r] = f2bf(hreg[4 + r]); }
      *(ushort4v*)(hn + l15 * 264 + cbase) = q0;
      *(ushort4v*)(hn + l15 * 264 + cbase + 16) = q1;
    }

    // raw barrier: drain LDS only; VMEM prefetches stay in flight across the step boundary.
    __builtin_amdgcn_sched_barrier(0);
    asm volatile("s_waitcnt lgkmcnt(0)" ::: "memory");
    __builtin_amdgcn_s_barrier();
    __builtin_amdgcn_sched_barrier(0);
  }

  // h_last
  {
    float4v o0 = {hreg[0], hreg[1], hreg[2], hreg[3]};
    float4v o1 = {hreg[4], hreg[5], hreg[6], hreg[7]};
    *(float4v*)(out + HLAST_OFF + (size_t)bg * 256 + cbase) = o0;
    *(float4v*)(out + HLAST_OFF + (size_t)bg * 256 + cbase + 16) = o1;
  }
}

extern "C" void kernel_launch(void* const* d_in, const int* in_sizes, int n_in,
                              void* d_out, int out_size, void* d_ws, size_t ws_size,
                              hipStream_t stream) {
  const float* x = (const float*)d_in[0];
  const float* h0 = (const float*)d_in[1];
  const int* mask = (const int*)d_in[2];
  const float* Wih = (const float*)d_in[3];
  const float* Whh = (const float*)d_in[4];
  const float* bih = (const float*)d_in[5];
  const float* bhh = (const float*)d_in[6];
  float* out = (float*)d_out;
  int* wsi = (int*)d_ws;

  hipMemsetAsync(d_out, 0, (size_t)out_size * 4, stream);  // unmasked / padded positions emit 0

  k_prep<<<1, 512, 0, stream>>>(mask, wsi);
  k_build<<<512, 256, 0, stream>>>(mask, wsi);
  k_wcvt<<<384, 256, 0, stream>>>(Wih, Whh, wsi);
  k_gemm<<<dim3(1024, 6), 256, 0, stream>>>(x, bih, wsi);
  k_rec<<<16, 512, 0, stream>>>(bhh, h0, wsi, out);
}

// Round 5
// 1126.844 us; speedup vs baseline: 1.7361x; 1.7122x over previous
//
#include <hip/hip_runtime.h>
#include <stdint.h>

typedef unsigned short ushortT;
typedef __attribute__((ext_vector_type(8))) short short8;     // 8 x bf16 (MFMA frag)
typedef __attribute__((ext_vector_type(4))) float float4v;
typedef __attribute__((ext_vector_type(4))) int int4v;
typedef __attribute__((ext_vector_type(2))) int int2v;
typedef __attribute__((ext_vector_type(4))) unsigned short ushort4v;

// ---- workspace layout (bytes) ----
#define OFF_HDR      0            // int[3]: K, maxlen, mask_mode
#define OFF_LEN      8192         // int[256]
#define OFF_CUMM     12288        // int[512]
#define OFF_CUMP     16384        // int[512]
#define OFF_MTI      32768        // int[131072]  maskTrueIdx
#define OFF_PARR     557056       // int[131072]  p_array (packed rank or -1)
#define OFF_WIH      1605632      // bf16[768*256]
#define OFF_WHH      1998848      // bf16[768*256]
#define OFF_GI       2392064      // bf16[131072*768] input projections (packed order)

#define HLAST_OFF    33554432     // floats: T*B*H

__device__ __forceinline__ ushortT f2bf(float f) {
  unsigned u = __float_as_uint(f);
  unsigned r = (u + 0x7fffu + ((u >> 16) & 1u)) >> 16;
  return (ushortT)r;
}
__device__ __forceinline__ float bf2f(ushortT h) {
  return __uint_as_float(((unsigned)h) << 16);
}
__device__ __forceinline__ float sigf(float x) { return 1.f / (1.f + __expf(-x)); }
__device__ __forceinline__ float tanhfast(float x) { return 1.f - 2.f / (1.f + __expf(2.f * x)); }

// ---------------- k_prep: lengths, row/col sums, scans, mask dtype detect ----------------
__global__ __launch_bounds__(512) void k_prep(const int* __restrict__ mask, int* __restrict__ wsi) {
  __shared__ int m_s[512], colp[512], len_s[256], sA[512], sB[512];
  __shared__ int sh_mode;
  const int tid = threadIdx.x;
  if (tid == 0) sh_mode = 0;
  __syncthreads();
  int bad = 0;
  for (int i = tid; i < 32768; i += 512) {
    unsigned v = ((const unsigned*)mask)[i];
    if (v > 1u) bad = 1;
  }
  if (bad) atomicOr(&sh_mode, 1);
  __syncthreads();
  const int mode = sh_mode;

  int s = 0;
  if (mode) {
    const unsigned char* mb = (const unsigned char*)mask;
    for (int c = 0; c < 256; c += 4) {
      unsigned v = *(const unsigned*)(mb + tid * 256 + c);
      s += (v & 0xff) + ((v >> 8) & 0xff) + ((v >> 16) & 0xff) + ((v >> 24) & 0xff);
    }
  } else {
    const int4v* mr = (const int4v*)(mask + tid * 256);
    for (int c = 0; c < 64; ++c) { int4v v = mr[c]; s += v[0] + v[1] + v[2] + v[3]; }
  }
  m_s[tid] = s;

  const int b = tid & 255, hh = tid >> 8;
  int cs = 0;
  if (mode) {
    const unsigned char* mb = (const unsigned char*)mask;
    for (int r = hh * 256; r < hh * 256 + 256; ++r) cs += mb[r * 256 + b];
  } else {
    for (int r = hh * 256; r < hh * 256 + 256; ++r) cs += mask[r * 256 + b];
  }
  colp[tid] = cs;
  __syncthreads();
  if (tid < 256) len_s[tid] = colp[tid] + colp[tid + 256];
  __syncthreads();

  int nt = 0;
  for (int i = 0; i < 256; ++i) nt += (len_s[i] > tid) ? 1 : 0;

  sA[tid] = m_s[tid]; sB[tid] = nt;
  for (int off = 1; off < 512; off <<= 1) {
    __syncthreads();
    int am = (tid >= off) ? sA[tid - off] : 0;
    int an = (tid >= off) ? sB[tid - off] : 0;
    __syncthreads();
    sA[tid] += am; sB[tid] += an;
  }
  __syncthreads();
  wsi[OFF_CUMM / 4 + tid] = sA[tid] - m_s[tid];
  wsi[OFF_CUMP / 4 + tid] = sB[tid] - nt;
  if (tid < 256) wsi[OFF_LEN / 4 + tid] = len_s[tid];

  colp[tid] = (tid < 256) ? len_s[tid] : 0;
  for (int off = 256; off >= 1; off >>= 1) {
    __syncthreads();
    int o = (tid < off) ? colp[tid + off] : 0;
    __syncthreads();
    if (tid < off) colp[tid] = max(colp[tid], o);
  }
  __syncthreads();
  if (tid == 0) { wsi[0] = sA[511]; wsi[1] = colp[0]; wsi[2] = mode; }
}

// ---------------- k_build: per-row scans -> maskTrueIdx and p_array ----------------
__global__ __launch_bounds__(256) void k_build(const int* __restrict__ mask, int* __restrict__ wsi) {
  const int t = blockIdx.x, b = threadIdx.x;
  const int mode = wsi[2];
  const int lane = b & 63, wv = b >> 6;
  int mflag = mode ? (int)((const unsigned char*)mask)[t * 256 + b] : mask[t * 256 + b];
  mflag = mflag ? 1 : 0;
  const int len = wsi[OFF_LEN / 4 + b];
  const int pflag = (t < len) ? 1 : 0;
  unsigned long long bm = __ballot(mflag), bp = __ballot(pflag);
  __shared__ int wm[4], wp[4];
  if (lane == 0) { wm[wv] = __popcll(bm); wp[wv] = __popcll(bp); }
  __syncthreads();
  int baseM = 0, baseP = 0;
  for (int i = 0; i < wv; ++i) { baseM += wm[i]; baseP += wp[i]; }
  unsigned long long lt = (1ull << lane) - 1ull;
  const int moff = baseM + __popcll(bm & lt);
  const int poff = baseP + __popcll(bp & lt);
  const int j = t * 256 + b;
  if (mflag) wsi[OFF_MTI / 4 + wsi[OFF_CUMM / 4 + t] + moff] = j;
  wsi[OFF_PARR / 4 + j] = pflag ? (wsi[OFF_CUMP / 4 + t] + poff) : -1;
}

// ---------------- k_wcvt: W_ih, W_hh fp32 -> bf16 ----------------
__global__ __launch_bounds__(256) void k_wcvt(const float* __restrict__ Wih,
                                              const float* __restrict__ Whh,
                                              int* __restrict__ wsi) {
  const int idx = (blockIdx.x * 256 + threadIdx.x) * 4;
  const float* src;
  ushortT* dst;
  if (idx < 196608) { src = Wih + idx; dst = (ushortT*)((char*)wsi + OFF_WIH) + idx; }
  else { src = Whh + (idx - 196608); dst = (ushortT*)((char*)wsi + OFF_WHH) + (idx - 196608); }
  float4v v = *(const float4v*)src;
  ushort4v o;
  o[0] = f2bf(v[0]); o[1] = f2bf(v[1]); o[2] = f2bf(v[2]); o[3] = f2bf(v[3]);
  *(ushort4v*)dst = o;
}

// -------- k_gemm: gi[p] = bf16( x[mti[p]] @ W_ih^T + b_ih + [bhh for r,z rows] ) ----------
// b_hh for the r and z gates is foldable here (enters the sigmoid additively); the n-gate's
// b_hh is multiplied by r in the GRU cell and stays separate (added in k_rec).
__global__ __launch_bounds__(256, 2) void k_gemm(const float* __restrict__ x,
                                                 const float* __restrict__ bih,
                                                 const float* __restrict__ bhh,
                                                 int* __restrict__ wsi) {
  const int K = wsi[0];
  const int m0 = blockIdx.x * 128;
  if (m0 >= K) return;
  const int n0 = blockIdx.y * 128;
  char* wsc = (char*)wsi;
  const ushortT* Bw = (const ushortT*)(wsc + OFF_WIH);
  ushortT* C = (ushortT*)(wsc + OFF_GI);
  __shared__ ushortT As[128 * 72], Bs[128 * 72];
  __shared__ int mti_s[128];
  const int tid = threadIdx.x, w = tid >> 6, lane = tid & 63;
  const int l15 = lane & 15, quad = lane >> 4;
  if (tid < 128) {
    int m = m0 + tid;
    mti_s[tid] = (m < K) ? wsi[OFF_MTI / 4 + m] : 0;
  }
  float biasj[4];
#pragma unroll
  for (int j = 0; j < 4; ++j) {
    int n = n0 + (w & 1) * 64 + j * 16 + l15;
    biasj[j] = bih[n] + ((n < 512) ? bhh[n] : 0.f);
  }
  float4v acc[4][4];
#pragma unroll
  for (int i = 0; i < 4; ++i)
#pragma unroll
    for (int j = 0; j < 4; ++j) acc[i][j] = (float4v){0.f, 0.f, 0.f, 0.f};

  for (int k0 = 0; k0 < 256; k0 += 64) {
    __syncthreads();
#pragma unroll
    for (int i = 0; i < 8; ++i) {          // A: gather 128 rows x 64 k (fp32 -> bf16)
      int cid = i * 256 + tid;
      int row = cid >> 4, c4 = cid & 15;
      float4v v = *(const float4v*)(x + (size_t)mti_s[row] * 256 + k0 + c4 * 4);
      ushort4v o;
      o[0] = f2bf(v[0]); o[1] = f2bf(v[1]); o[2] = f2bf(v[2]); o[3] = f2bf(v[3]);
      *(ushort4v*)(As + row * 72 + c4 * 4) = o;
    }
#pragma unroll
    for (int i = 0; i < 4; ++i) {          // B: W_ih bf16
      int cid = i * 256 + tid;
      int row = cid >> 3, c8 = cid & 7;
      int4v vb = *(const int4v*)(Bw + (size_t)(n0 + row) * 256 + k0 + c8 * 8);
      *(int4v*)(Bs + row * 72 + c8 * 8) = vb;
    }
    __syncthreads();
#pragma unroll
    for (int kk = 0; kk < 2; ++kk) {
      short8 af[4], bfr[4];
#pragma unroll
      for (int i = 0; i < 4; ++i)
        af[i] = *(const short8*)(As + ((w >> 1) * 64 + i * 16 + l15) * 72 + kk * 32 + quad * 8);
#pragma unroll
      for (int j = 0; j < 4; ++j)
        bfr[j] = *(const short8*)(Bs + ((w & 1) * 64 + j * 16 + l15) * 72 + kk * 32 + quad * 8);
#pragma unroll
      for (int i = 0; i < 4; ++i)
#pragma unroll
        for (int j = 0; j < 4; ++j)
          acc[i][j] = __builtin_amdgcn_mfma_f32_16x16x32_bf16(af[i], bfr[j], acc[i][j], 0, 0, 0);
    }
  }
#pragma unroll
  for (int i = 0; i < 4; ++i) {
    int m = m0 + (w >> 1) * 64 + i * 16 + quad * 4;
#pragma unroll
    for (int j = 0; j < 4; ++j) {
      int n = n0 + (w & 1) * 64 + j * 16 + l15;
#pragma unroll
      for (int r = 0; r < 4; ++r)
        if (m + r < K) C[(size_t)(m + r) * 768 + n] = f2bf(acc[i][j][r] + biasj[j]);
    }
  }
}

// ---------------- k_rec: GRU recurrence, hybrid-resident W_hh (regs + LDS) -----------------
// 16 blocks x 512 threads (8 waves, 2/SIMD, 1 block/CU). Wave w owns h-cols [32w, 32w+32).
// ROUND-4 POST-MORTEM: streaming all 384KB of W_hh from L2 every step is L2-BW-bound
// (~6000 cy/step at ~60B/cy/CU). Fix: W_hh never touches global in the loop.
//   - r,z-gate tiles (256KB/CU) resident in registers: wf[4][8] = 128 VGPR/lane.
//   - n-gate tiles (128KB/CU) resident in LDS (dynamic, 144KB total), lane-linear
//     ds_read_b128 (conflict-free), read at LDS BW ~2x L2 BW.
//   - h stored in MFMA-B-fragment order hlin[kk][lane] -> lane-linear reads (kills the
//     8-way bank conflict of the old 264-stride layout).
// In-register gates; one raw s_barrier/step (lgkmcnt-only drain; gi prefetch stays in
// flight across the barrier). bhh_r/z folded into gi (k_gemm); bhh_n kept (mult by r).
__device__ __forceinline__ void giload(int2v* R, int2v* Z, int2v* N,
                                       const ushortT* __restrict__ gib, int p, int w, int quad) {
  const size_t pb = (size_t)max(p, 0) * 768 + 32 * w + quad * 4;
#pragma unroll
  for (int hh = 0; hh < 2; ++hh) {
    R[hh] = *(const int2v*)(gib + pb + hh * 16);
    Z[hh] = *(const int2v*)(gib + pb + 256 + hh * 16);
    N[hh] = *(const int2v*)(gib + pb + 512 + hh * 16);
  }
}

__global__ __launch_bounds__(512, 2) void k_rec(const float* __restrict__ bhh,
                                                const float* __restrict__ h0,
                                                int* __restrict__ wsi,
                                                float* __restrict__ out) {
  extern __shared__ char smem_dyn[];
  ushortT* hlin = (ushortT*)smem_dyn;                 // 2 bufs x 8 kk x 64 lanes x 8 ushort = 16KB
  short8* wlds = (short8*)(smem_dyn + 16384);         // 8 waves x 16 units x 64 lanes x 16B = 128KB

  const int b0 = blockIdx.x * 16;
  const int tid = threadIdx.x;
  const int w = tid >> 6, lane = tid & 63, l15 = lane & 15, quad = lane >> 4;
  char* wsc = (char*)wsi;
  const ushortT* Whh = (const ushortT*)(wsc + OFF_WHH);
  const ushortT* gib = (const ushortT*)(wsc + OFF_GI);
  const int* parr = wsi + OFF_PARR / 4;
  const int* mti = wsi + OFF_MTI / 4;
  const int K = wsi[0];
  const int bg = b0 + l15;                 // this lane's batch
  const int cbase = 32 * w + quad * 4;     // first h-column of run hh=0 (hh=1 adds +16)

  // h-write coords in fragment layout: kk-row = w; lane lam, ushort offset off
  const int lam0 = ((quad >> 1)) * 16 + l15;          // hh=0
  const int lam1 = (2 + (quad >> 1)) * 16 + l15;      // hh=1
  const int hoff = (quad & 1) * 4;

  // block tmax = max length over the 16 batches (same in all waves)
  int tmax = wsi[OFF_LEN / 4 + bg];
#pragma unroll
  for (int o = 1; o < 16; o <<= 1) tmax = max(tmax, __shfl_xor(tmax, o));

  // n-gate bhh (multiplied by r in the cell -> cannot be folded into gi)
  float4v bIn[2];
#pragma unroll
  for (int hh = 0; hh < 2; ++hh)
    bIn[hh] = *(const float4v*)(bhh + 512 + cbase + hh * 16);

  // resident W (r,z gates): tiles 0..3, 128 VGPR/lane
  short8 wf[4][8];
#pragma unroll
  for (int tt = 0; tt < 4; ++tt) {
    const int row = (tt >> 1) * 256 + 32 * w + (tt & 1) * 16 + l15;
#pragma unroll
    for (int kk = 0; kk < 8; ++kk)
      wf[tt][kk] = *(const short8*)(Whh + (size_t)row * 256 + kk * 32 + quad * 8);
  }
  // LDS W (n gate): tiles 4,5 -> wlds, already in per-lane fragment order
#pragma unroll
  for (int tt = 0; tt < 2; ++tt) {
    const int row = 512 + 32 * w + tt * 16 + l15;
#pragma unroll
    for (int kk = 0; kk < 8; ++kk) {
      short8 v = *(const short8*)(Whh + (size_t)row * 256 + kk * 32 + quad * 8);
      wlds[(w * 16 + tt * 8 + kk) * 64 + lane] = v;
    }
  }

  // h0 -> hreg (f32, persistent) + hlin[0] (bf16, fragment order)
  float hreg[8];
  {
    float4v a = *(const float4v*)(h0 + (size_t)bg * 256 + cbase);
    float4v b = *(const float4v*)(h0 + (size_t)bg * 256 + cbase + 16);
    ushort4v pa, pb;
#pragma unroll
    for (int r = 0; r < 4; ++r) {
      hreg[r] = a[r]; hreg[4 + r] = b[r];
      pa[r] = f2bf(a[r]); pb[r] = f2bf(b[r]);
    }
    *(ushort4v*)(hlin + (w * 64 + lam0) * 8 + hoff) = pa;
    *(ushort4v*)(hlin + (w * 64 + lam1) * 8 + hoff) = pb;
  }

  // gi / parr / mti prologue (t = 0, 1)
  int p0 = parr[bg], p1 = parr[256 + bg];
  int m0 = mti[bg], m1 = mti[256 + bg];
  int2v g0R[2], g0Z[2], g0N[2], g1R[2], g1Z[2], g1N[2];
  giload(g0R, g0Z, g0N, gib, p0, w, quad);
  giload(g1R, g1Z, g1N, gib, p1, w, quad);

  __syncthreads();

  for (int t = 0; t < tmax; ++t) {
    // prefetch step t+2 metadata (used at the bottom of this step)
    int p2 = -1, m2 = 0;
    if (t + 2 < 512) {
      p2 = parr[(t + 2) * 256 + bg];
      m2 = mti[(t + 2) * 256 + bg];
    }

    // [A] gh = W_hh @ h^T : resident wf for r,z; LDS W for n; h from fragment-layout LDS
    float4v acc[6];
#pragma unroll
    for (int i = 0; i < 6; ++i) acc[i] = (float4v){0.f, 0.f, 0.f, 0.f};
    {
      const ushortT* hb = hlin + (t & 1) * 4096;
#pragma unroll
      for (int kk = 0; kk < 8; ++kk) {
        short8 hf = *(const short8*)(hb + (kk * 64 + lane) * 8);
        short8 w4 = wlds[(w * 16 + kk) * 64 + lane];
        short8 w5 = wlds[(w * 16 + 8 + kk) * 64 + lane];
        acc[0] = __builtin_amdgcn_mfma_f32_16x16x32_bf16(wf[0][kk], hf, acc[0], 0, 0, 0);
        acc[1] = __builtin_amdgcn_mfma_f32_16x16x32_bf16(wf[1][kk], hf, acc[1], 0, 0, 0);
        acc[2] = __builtin_amdgcn_mfma_f32_16x16x32_bf16(wf[2][kk], hf, acc[2], 0, 0, 0);
        acc[3] = __builtin_amdgcn_mfma_f32_16x16x32_bf16(wf[3][kk], hf, acc[3], 0, 0, 0);
        acc[4] = __builtin_amdgcn_mfma_f32_16x16x32_bf16(w4, hf, acc[4], 0, 0, 0);
        acc[5] = __builtin_amdgcn_mfma_f32_16x16x32_bf16(w5, hf, acc[5], 0, 0, 0);
      }
    }

    // [B] gates, fully in registers. gi already contains bih (+bhh for r,z).
    const bool valid = (p0 >= 0);
#pragma unroll
    for (int hh = 0; hh < 2; ++hh)
#pragma unroll
      for (int r = 0; r < 4; ++r) {
        float gir = bf2f((ushortT)(((unsigned)g0R[hh][r >> 1]) >> ((r & 1) * 16)));
        float giz = bf2f((ushortT)(((unsigned)g0Z[hh][r >> 1]) >> ((r & 1) * 16)));
        float gin = bf2f((ushortT)(((unsigned)g0N[hh][r >> 1]) >> ((r & 1) * 16)));
        float rr = sigf(gir + acc[hh][r]);                       // r-gate
        float zz = sigf(giz + acc[2 + hh][r]);                   // z-gate
        float nn = tanhfast(gin + rr * (acc[4 + hh][r] + bIn[hh][r]));  // n-gate
        float hv = nn + zz * (hreg[hh * 4 + r] - nn);
        hreg[hh * 4 + r] = valid ? hv : hreg[hh * 4 + r];
      }

    // scores scatter (packed row t*256+bg -> masked position mti[...])
    const int nflat = t * 256 + bg;
    if (valid && nflat < K) {
      float4v o0 = {hreg[0], hreg[1], hreg[2], hreg[3]};
      float4v o1 = {hreg[4], hreg[5], hreg[6], hreg[7]};
      *(float4v*)(out + (size_t)m0 * 256 + cbase) = o0;
      *(float4v*)(out + (size_t)m0 * 256 + cbase + 16) = o1;
    }

    // rotate gi pipeline; issue next loads (stay in flight across the raw barrier)
#pragma unroll
    for (int hh = 0; hh < 2; ++hh) { g0R[hh] = g1R[hh]; g0Z[hh] = g1Z[hh]; g0N[hh] = g1N[hh]; }
    giload(g1R, g1Z, g1N, gib, p2, w, quad);
    p0 = p1; p1 = p2; m0 = m1; m1 = m2;

    // h -> next LDS buffer (fragment order)
    {
      ushort4v q0, q1;
#pragma unroll
      for (int r = 0; r < 4; ++r) { q0[r] = f2bf(hreg[r]); q1[r] = f2bf(hreg[4 + r]); }
      ushortT* hbn = hlin + ((t + 1) & 1) * 4096;
      *(ushort4v*)(hbn + (w * 64 + lam0) * 8 + hoff) = q0;
      *(ushort4v*)(hbn + (w * 64 + lam1) * 8 + hoff) = q1;
    }

    // raw barrier: drain LDS only; VMEM prefetches stay in flight across the step boundary.
    __builtin_amdgcn_sched_barrier(0);
    asm volatile("s_waitcnt lgkmcnt(0)" ::: "memory");
    __builtin_amdgcn_s_barrier();
    __builtin_amdgcn_sched_barrier(0);
  }

  // h_last
  {
    float4v o0 = {hreg[0], hreg[1], hreg[2], hreg[3]};
    float4v o1 = {hreg[4], hreg[5], hreg[6], hreg[7]};
    *(float4v*)(out + HLAST_OFF + (size_t)bg * 256 + cbase) = o0;
    *(float4v*)(out + HLAST_OFF + (size_t)bg * 256 + cbase + 16) = o1;
  }
}

extern "C" void kernel_launch(void* const* d_in, const int* in_sizes, int n_in,
                              void* d_out, int out_size, void* d_ws, size_t ws_size,
                              hipStream_t stream) {
  const float* x = (const float*)d_in[0];
  const float* h0 = (const float*)d_in[1];
  const int* mask = (const int*)d_in[2];
  const float* Wih = (const float*)d_in[3];
  const float* Whh = (const float*)d_in[4];
  const float* bih = (const float*)d_in[5];
  const float* bhh = (const float*)d_in[6];
  float* out = (float*)d_out;
  int* wsi = (int*)d_ws;

  hipMemsetAsync(d_out, 0, (size_t)out_size * 4, stream);  // unmasked / padded positions emit 0

  const int lds_bytes = 16384 + 131072;  // hlin (16KB) + wlds (128KB) = 144KB dynamic LDS
  hipFuncSetAttribute((const void*)k_rec, hipFuncAttributeMaxDynamicSharedMemorySize, lds_bytes);

  k_prep<<<1, 512, 0, stream>>>(mask, wsi);
  k_build<<<512, 256, 0, stream>>>(mask, wsi);
  k_wcvt<<<384, 256, 0, stream>>>(Wih, Whh, wsi);
  k_gemm<<<dim3(1024, 6), 256, 0, stream>>>(x, bih, bhh, wsi);
  k_rec<<<16, 512, lds_bytes, stream>>>(bhh, h0, wsi, out);
}

// Round 7
// 858.205 us; speedup vs baseline: 2.2795x; 1.3130x over previous
//
#include <hip/hip_runtime.h>
#include <stdint.h>

typedef unsigned short ushortT;
typedef __attribute__((ext_vector_type(8))) short short8;     // 8 x bf16 (MFMA frag)
typedef __attribute__((ext_vector_type(4))) float float4v;
typedef __attribute__((ext_vector_type(4))) int int4v;
typedef __attribute__((ext_vector_type(2))) int int2v;
typedef __attribute__((ext_vector_type(4))) unsigned short ushort4v;

// ---- workspace layout (bytes) ----
#define OFF_HDR      0            // int[3]: K, maxlen, mask_mode
#define OFF_LEN      8192         // int[256]
#define OFF_CUMM     12288        // int[512]
#define OFF_CUMP     16384        // int[512]
#define OFF_MTI      32768        // int[131072]  maskTrueIdx
#define OFF_PARR     557056       // int[131072]  p_array (packed rank or -1)
#define OFF_WIH      1605632      // bf16[768*256]
#define OFF_WHH      1998848      // bf16[768*256]
#define OFF_GI       2392064      // bf16[131072*768] input projections (packed order)

#define HLAST_OFF    33554432     // floats: T*B*H

__device__ __forceinline__ ushortT f2bf(float f) {
  unsigned u = __float_as_uint(f);
  unsigned r = (u + 0x7fffu + ((u >> 16) & 1u)) >> 16;
  return (ushortT)r;
}
__device__ __forceinline__ float bf2f(ushortT h) {
  return __uint_as_float(((unsigned)h) << 16);
}
__device__ __forceinline__ float sigf(float x) { return 1.f / (1.f + __expf(-x)); }
__device__ __forceinline__ float tanhfast(float x) { return 1.f - 2.f / (1.f + __expf(2.f * x)); }
__device__ __forceinline__ unsigned cvtpk(float lo, float hi) {   // RNE, lo -> bits[15:0]
  unsigned r;
  asm("v_cvt_pk_bf16_f32 %0, %1, %2" : "=v"(r) : "v"(lo), "v"(hi));
  return r;
}

// ---------------- k_prep: lengths, row/col sums, scans, mask dtype detect ----------------
__global__ __launch_bounds__(512) void k_prep(const int* __restrict__ mask, int* __restrict__ wsi) {
  __shared__ int m_s[512], colp[512], len_s[256], sA[512], sB[512];
  __shared__ int sh_mode;
  const int tid = threadIdx.x;
  if (tid == 0) sh_mode = 0;
  __syncthreads();
  int bad = 0;
  for (int i = tid; i < 32768; i += 512) {
    unsigned v = ((const unsigned*)mask)[i];
    if (v > 1u) bad = 1;
  }
  if (bad) atomicOr(&sh_mode, 1);
  __syncthreads();
  const int mode = sh_mode;

  int s = 0;
  if (mode) {
    const unsigned char* mb = (const unsigned char*)mask;
    for (int c = 0; c < 256; c += 4) {
      unsigned v = *(const unsigned*)(mb + tid * 256 + c);
      s += (v & 0xff) + ((v >> 8) & 0xff) + ((v >> 16) & 0xff) + ((v >> 24) & 0xff);
    }
  } else {
    const int4v* mr = (const int4v*)(mask + tid * 256);
    for (int c = 0; c < 64; ++c) { int4v v = mr[c]; s += v[0] + v[1] + v[2] + v[3]; }
  }
  m_s[tid] = s;

  const int b = tid & 255, hh = tid >> 8;
  int cs = 0;
  if (mode) {
    const unsigned char* mb = (const unsigned char*)mask;
    for (int r = hh * 256; r < hh * 256 + 256; ++r) cs += mb[r * 256 + b];
  } else {
    for (int r = hh * 256; r < hh * 256 + 256; ++r) cs += mask[r * 256 + b];
  }
  colp[tid] = cs;
  __syncthreads();
  if (tid < 256) len_s[tid] = colp[tid] + colp[tid + 256];
  __syncthreads();

  int nt = 0;
  for (int i = 0; i < 256; ++i) nt += (len_s[i] > tid) ? 1 : 0;

  sA[tid] = m_s[tid]; sB[tid] = nt;
  for (int off = 1; off < 512; off <<= 1) {
    __syncthreads();
    int am = (tid >= off) ? sA[tid - off] : 0;
    int an = (tid >= off) ? sB[tid - off] : 0;
    __syncthreads();
    sA[tid] += am; sB[tid] += an;
  }
  __syncthreads();
  wsi[OFF_CUMM / 4 + tid] = sA[tid] - m_s[tid];
  wsi[OFF_CUMP / 4 + tid] = sB[tid] - nt;
  if (tid < 256) wsi[OFF_LEN / 4 + tid] = len_s[tid];

  colp[tid] = (tid < 256) ? len_s[tid] : 0;
  for (int off = 256; off >= 1; off >>= 1) {
    __syncthreads();
    int o = (tid < off) ? colp[tid + off] : 0;
    __syncthreads();
    if (tid < off) colp[tid] = max(colp[tid], o);
  }
  __syncthreads();
  if (tid == 0) { wsi[0] = sA[511]; wsi[1] = colp[0]; wsi[2] = mode; }
}

// ---------------- k_build: per-row scans -> maskTrueIdx and p_array ----------------
__global__ __launch_bounds__(256) void k_build(const int* __restrict__ mask, int* __restrict__ wsi) {
  const int t = blockIdx.x, b = threadIdx.x;
  const int mode = wsi[2];
  const int lane = b & 63, wv = b >> 6;
  int mflag = mode ? (int)((const unsigned char*)mask)[t * 256 + b] : mask[t * 256 + b];
  mflag = mflag ? 1 : 0;
  const int len = wsi[OFF_LEN / 4 + b];
  const int pflag = (t < len) ? 1 : 0;
  unsigned long long bm = __ballot(mflag), bp = __ballot(pflag);
  __shared__ int wm[4], wp[4];
  if (lane == 0) { wm[wv] = __popcll(bm); wp[wv] = __popcll(bp); }
  __syncthreads();
  int baseM = 0, baseP = 0;
  for (int i = 0; i < wv; ++i) { baseM += wm[i]; baseP += wp[i]; }
  unsigned long long lt = (1ull << lane) - 1ull;
  const int moff = baseM + __popcll(bm & lt);
  const int poff = baseP + __popcll(bp & lt);
  const int j = t * 256 + b;
  if (mflag) wsi[OFF_MTI / 4 + wsi[OFF_CUMM / 4 + t] + moff] = j;
  wsi[OFF_PARR / 4 + j] = pflag ? (wsi[OFF_CUMP / 4 + t] + poff) : -1;
}

// ---------------- k_wcvt: W_ih, W_hh fp32 -> bf16 ----------------
__global__ __launch_bounds__(256) void k_wcvt(const float* __restrict__ Wih,
                                              const float* __restrict__ Whh,
                                              int* __restrict__ wsi) {
  const int idx = (blockIdx.x * 256 + threadIdx.x) * 4;
  const float* src;
  ushortT* dst;
  if (idx < 196608) { src = Wih + idx; dst = (ushortT*)((char*)wsi + OFF_WIH) + idx; }
  else { src = Whh + (idx - 196608); dst = (ushortT*)((char*)wsi + OFF_WHH) + (idx - 196608); }
  float4v v = *(const float4v*)src;
  ushort4v o;
  o[0] = f2bf(v[0]); o[1] = f2bf(v[1]); o[2] = f2bf(v[2]); o[3] = f2bf(v[3]);
  *(ushort4v*)dst = o;
}

// -------- k_gemm: gi[p] = bf16( x[mti[p]] @ W_ih^T + b_ih + [bhh for r,z rows] ) ----------
// b_hh for the r and z gates is foldable here (enters the sigmoid additively); the n-gate's
// b_hh is multiplied by r in the GRU cell and stays separate (added in k_rec).
__global__ __launch_bounds__(256, 2) void k_gemm(const float* __restrict__ x,
                                                 const float* __restrict__ bih,
                                                 const float* __restrict__ bhh,
                                                 int* __restrict__ wsi) {
  const int K = wsi[0];
  const int m0 = blockIdx.x * 128;
  if (m0 >= K) return;
  const int n0 = blockIdx.y * 128;
  char* wsc = (char*)wsi;
  const ushortT* Bw = (const ushortT*)(wsc + OFF_WIH);
  ushortT* C = (ushortT*)(wsc + OFF_GI);
  __shared__ ushortT As[128 * 72], Bs[128 * 72];
  __shared__ int mti_s[128];
  const int tid = threadIdx.x, w = tid >> 6, lane = tid & 63;
  const int l15 = lane & 15, quad = lane >> 4;
  if (tid < 128) {
    int m = m0 + tid;
    mti_s[tid] = (m < K) ? wsi[OFF_MTI / 4 + m] : 0;
  }
  float biasj[4];
#pragma unroll
  for (int j = 0; j < 4; ++j) {
    int n = n0 + (w & 1) * 64 + j * 16 + l15;
    biasj[j] = bih[n] + ((n < 512) ? bhh[n] : 0.f);
  }
  float4v acc[4][4];
#pragma unroll
  for (int i = 0; i < 4; ++i)
#pragma unroll
    for (int j = 0; j < 4; ++j) acc[i][j] = (float4v){0.f, 0.f, 0.f, 0.f};

  for (int k0 = 0; k0 < 256; k0 += 64) {
    __syncthreads();
#pragma unroll
    for (int i = 0; i < 8; ++i) {          // A: gather 128 rows x 64 k (fp32 -> bf16)
      int cid = i * 256 + tid;
      int row = cid >> 4, c4 = cid & 15;
      float4v v = *(const float4v*)(x + (size_t)mti_s[row] * 256 + k0 + c4 * 4);
      ushort4v o;
      o[0] = f2bf(v[0]); o[1] = f2bf(v[1]); o[2] = f2bf(v[2]); o[3] = f2bf(v[3]);
      *(ushort4v*)(As + row * 72 + c4 * 4) = o;
    }
#pragma unroll
    for (int i = 0; i < 4; ++i) {          // B: W_ih bf16
      int cid = i * 256 + tid;
      int row = cid >> 3, c8 = cid & 7;
      int4v vb = *(const int4v*)(Bw + (size_t)(n0 + row) * 256 + k0 + c8 * 8);
      *(int4v*)(Bs + row * 72 + c8 * 8) = vb;
    }
    __syncthreads();
#pragma unroll
    for (int kk = 0; kk < 2; ++kk) {
      short8 af[4], bfr[4];
#pragma unroll
      for (int i = 0; i < 4; ++i)
        af[i] = *(const short8*)(As + ((w >> 1) * 64 + i * 16 + l15) * 72 + kk * 32 + quad * 8);
#pragma unroll
      for (int j = 0; j < 4; ++j)
        bfr[j] = *(const short8*)(Bs + ((w & 1) * 64 + j * 16 + l15) * 72 + kk * 32 + quad * 8);
#pragma unroll
      for (int i = 0; i < 4; ++i)
#pragma unroll
        for (int j = 0; j < 4; ++j)
          acc[i][j] = __builtin_amdgcn_mfma_f32_16x16x32_bf16(af[i], bfr[j], acc[i][j], 0, 0, 0);
    }
  }
#pragma unroll
  for (int i = 0; i < 4; ++i) {
    int m = m0 + (w >> 1) * 64 + i * 16 + quad * 4;
#pragma unroll
    for (int j = 0; j < 4; ++j) {
      int n = n0 + (w & 1) * 64 + j * 16 + l15;
#pragma unroll
      for (int r = 0; r < 4; ++r)
        if (m + r < K) C[(size_t)(m + r) * 768 + n] = f2bf(acc[i][j][r] + biasj[j]);
    }
  }
}

// ---------------- k_rec: GRU recurrence, 32 blocks x 8 batches, dup'd B columns -----------
// ROUND-5 POST-MORTEM: hybrid-resident W fixed the memory path; active-CU VALUBusy ~62%
// says gates/packing VALU on 16 CUs is now the critical path. Fix: split each 16-batch
// group into 2 blocks of 8 batches (32 blocks -> 32 CUs). B-fragment cols 8-15 carry a
// DUPLICATE of cols 0-7 (each thread dual-stores h into col lb and lb+8), so after MFMA
// every lane holds gh for its batch at both hh-halves locally: lane l15<8 consumes hh=0
// tiles, lane l15>=8 consumes hh=1 tiles — zero cross-lane ops. Per-thread per-step work
// halves: gates 8->4 els, gi loads 6->3, h-pack 4 f2bf -> 2 cvt_pk, out-store 2->1.
// W residency unchanged: r,z tiles in 128 regs/lane; n tiles in 128KB LDS (lane-linear).
// Raw s_barrier with lgkmcnt-only drain (VMEM prefetches stay in flight across steps).
__global__ __launch_bounds__(512, 2) void k_rec(const float* __restrict__ bhh,
                                                const float* __restrict__ h0,
                                                int* __restrict__ wsi,
                                                float* __restrict__ out) {
  extern __shared__ char smem_dyn[];
  ushortT* hlin = (ushortT*)smem_dyn;                 // 2 bufs x 8 kk x 64 lanes x 8 ushort = 16KB
  short8* wlds = (short8*)(smem_dyn + 16384);         // 8 waves x 16 units x 64 lanes x 16B = 128KB

  const int b0 = blockIdx.x * 8;
  const int tid = threadIdx.x;
  const int w = tid >> 6, lane = tid & 63, l15 = lane & 15, quad = lane >> 4;
  char* wsc = (char*)wsi;
  const ushortT* Whh = (const ushortT*)(wsc + OFF_WHH);
  const ushortT* gib = (const ushortT*)(wsc + OFF_GI);
  const int* parr = wsi + OFF_PARR / 4;
  const int* mti = wsi + OFF_MTI / 4;
  const int K = wsi[0];

  const int lb = l15 & 7;                  // this lane's batch within the block
  const int hs = l15 >> 3;                 // which hh-half this thread owns
  const int bg = b0 + lb;                  // global batch
  const int c0 = 32 * w + quad * 4 + hs * 16;   // thread's 4 h-columns: c0..c0+3

  // h-write slot in B-fragment layout (k-offset within wave block = quad*4 + hs*16 + r):
  const int lam = (hs * 2 + (quad >> 1)) * 16 + lb;   // dual store: lam and lam+8 (col lb, lb+8)
  const int hoff = (quad & 1) * 4;

  // block tmax = max length over the 8 batches (lanes duplicate across hs -> max over lb bits)
  int tmax = wsi[OFF_LEN / 4 + bg];
#pragma unroll
  for (int o = 1; o < 8; o <<= 1) tmax = max(tmax, __shfl_xor(tmax, o));

  // n-gate bhh for this thread's 4 cols (multiplied by r in the cell -> not foldable)
  float4v bIn = *(const float4v*)(bhh + 512 + c0);

  // resident W (r,z gates): tiles 0..3, 128 regs/lane
  short8 wf[4][8];
#pragma unroll
  for (int tt = 0; tt < 4; ++tt) {
    const int row = (tt >> 1) * 256 + 32 * w + (tt & 1) * 16 + l15;
#pragma unroll
    for (int kk = 0; kk < 8; ++kk)
      wf[tt][kk] = *(const short8*)(Whh + (size_t)row * 256 + kk * 32 + quad * 8);
  }
  // LDS W (n gate): tiles 4,5 -> wlds, already in per-lane fragment order
#pragma unroll
  for (int tt = 0; tt < 2; ++tt) {
    const int row = 512 + 32 * w + tt * 16 + l15;
#pragma unroll
    for (int kk = 0; kk < 8; ++kk) {
      short8 v = *(const short8*)(Whh + (size_t)row * 256 + kk * 32 + quad * 8);
      wlds[(w * 16 + tt * 8 + kk) * 64 + lane] = v;
    }
  }

  // h0 -> hreg (f32, persistent) + hlin[0] (bf16, fragment order, dual-store)
  float hreg[4];
  {
    float4v a = *(const float4v*)(h0 + (size_t)bg * 256 + c0);
#pragma unroll
    for (int r = 0; r < 4; ++r) hreg[r] = a[r];
    int2v pk = {(int)cvtpk(a[0], a[1]), (int)cvtpk(a[2], a[3])};
    *(int2v*)(hlin + (w * 64 + lam) * 8 + hoff) = pk;
    *(int2v*)(hlin + (w * 64 + lam + 8) * 8 + hoff) = pk;
  }

  // gi / parr / mti prologue (t = 0, 1)
  int p0 = parr[bg], p1 = parr[256 + bg];
  int m0 = mti[bg], m1 = mti[256 + bg];
  int2v g0R, g0Z, g0N, g1R, g1Z, g1N;
  {
    size_t pb = (size_t)max(p0, 0) * 768 + c0;
    g0R = *(const int2v*)(gib + pb);
    g0Z = *(const int2v*)(gib + pb + 256);
    g0N = *(const int2v*)(gib + pb + 512);
    pb = (size_t)max(p1, 0) * 768 + c0;
    g1R = *(const int2v*)(gib + pb);
    g1Z = *(const int2v*)(gib + pb + 256);
    g1N = *(const int2v*)(gib + pb + 512);
  }

  __syncthreads();

  for (int t = 0; t < tmax; ++t) {
    // prefetch step t+2 metadata (used at the bottom of this step)
    int p2 = -1, m2 = 0;
    if (t + 2 < 512) {
      p2 = parr[(t + 2) * 256 + bg];
      m2 = mti[(t + 2) * 256 + bg];
    }

    // [A] gh = W_hh @ h^T : resident wf for r,z; LDS W for n; h from fragment-layout LDS
    float4v acc[6];
#pragma unroll
    for (int i = 0; i < 6; ++i) acc[i] = (float4v){0.f, 0.f, 0.f, 0.f};
    {
      const ushortT* hb = hlin + (t & 1) * 4096;
#pragma unroll
      for (int kk = 0; kk < 8; ++kk) {
        short8 hf = *(const short8*)(hb + (kk * 64 + lane) * 8);
        short8 w4 = wlds[(w * 16 + kk) * 64 + lane];
        short8 w5 = wlds[(w * 16 + 8 + kk) * 64 + lane];
        acc[0] = __builtin_amdgcn_mfma_f32_16x16x32_bf16(wf[0][kk], hf, acc[0], 0, 0, 0);
        acc[1] = __builtin_amdgcn_mfma_f32_16x16x32_bf16(wf[1][kk], hf, acc[1], 0, 0, 0);
        acc[2] = __builtin_amdgcn_mfma_f32_16x16x32_bf16(wf[2][kk], hf, acc[2], 0, 0, 0);
        acc[3] = __builtin_amdgcn_mfma_f32_16x16x32_bf16(wf[3][kk], hf, acc[3], 0, 0, 0);
        acc[4] = __builtin_amdgcn_mfma_f32_16x16x32_bf16(w4, hf, acc[4], 0, 0, 0);
        acc[5] = __builtin_amdgcn_mfma_f32_16x16x32_bf16(w5, hf, acc[5], 0, 0, 0);
      }
    }

    // [B] gates for this thread's hh-half only (4 elements), fully in registers.
    // Static acc indexing via cndmask selects (runtime-indexed ext_vector -> scratch, rule 20).
    const bool valid = (p0 >= 0);
    const float4v accR = hs ? acc[1] : acc[0];
    const float4v accZ = hs ? acc[3] : acc[2];
    const float4v accN = hs ? acc[5] : acc[4];
#pragma unroll
    for (int r = 0; r < 4; ++r) {
      float gir = bf2f((ushortT)(((unsigned)g0R[r >> 1]) >> ((r & 1) * 16)));
      float giz = bf2f((ushortT)(((unsigned)g0Z[r >> 1]) >> ((r & 1) * 16)));
      float gin = bf2f((ushortT)(((unsigned)g0N[r >> 1]) >> ((r & 1) * 16)));
      float rr = sigf(gir + accR[r]);                       // r-gate (bhh folded in gi)
      float zz = sigf(giz + accZ[r]);                       // z-gate
      float nn = tanhfast(gin + rr * (accN[r] + bIn[r]));   // n-gate
      float hv = nn + zz * (hreg[r] - nn);
      hreg[r] = valid ? hv : hreg[r];
    }

    // scores scatter (packed row t*256+bg -> masked position mti[...])
    const int nflat = t * 256 + bg;
    if (valid && nflat < K) {
      float4v o0 = {hreg[0], hreg[1], hreg[2], hreg[3]};
      *(float4v*)(out + (size_t)m0 * 256 + c0) = o0;
    }

    // rotate gi pipeline; issue next loads (stay in flight across the raw barrier)
    g0R = g1R; g0Z = g1Z; g0N = g1N;
    {
      size_t pb = (size_t)max(p2, 0) * 768 + c0;
      g1R = *(const int2v*)(gib + pb);
      g1Z = *(const int2v*)(gib + pb + 256);
      g1N = *(const int2v*)(gib + pb + 512);
    }
    p0 = p1; p1 = p2; m0 = m1; m1 = m2;

    // h -> next LDS buffer (fragment order, dual-store: col lb and lb+8)
    {
      int2v pk = {(int)cvtpk(hreg[0], hreg[1]), (int)cvtpk(hreg[2], hreg[3])};
      ushortT* hbn = hlin + ((t + 1) & 1) * 4096;
      *(int2v*)(hbn + (w * 64 + lam) * 8 + hoff) = pk;
      *(int2v*)(hbn + (w * 64 + lam + 8) * 8 + hoff) = pk;
    }

    // raw barrier: drain LDS only; VMEM prefetches stay in flight across the step boundary.
    __builtin_amdgcn_sched_barrier(0);
    asm volatile("s_waitcnt lgkmcnt(0)" ::: "memory");
    __builtin_amdgcn_s_barrier();
    __builtin_amdgcn_sched_barrier(0);
  }

  // h_last (threads hs=0/1 cover disjoint col-ranges of each batch)
  {
    float4v o0 = {hreg[0], hreg[1], hreg[2], hreg[3]};
    *(float4v*)(out + HLAST_OFF + (size_t)bg * 256 + c0) = o0;
  }
}

extern "C" void kernel_launch(void* const* d_in, const int* in_sizes, int n_in,
                              void* d_out, int out_size, void* d_ws, size_t ws_size,
                              hipStream_t stream) {
  const float* x = (const float*)d_in[0];
  const float* h0 = (const float*)d_in[1];
  const int* mask = (const int*)d_in[2];
  const float* Wih = (const float*)d_in[3];
  const float* Whh = (const float*)d_in[4];
  const float* bih = (const float*)d_in[5];
  const float* bhh = (const float*)d_in[6];
  float* out = (float*)d_out;
  int* wsi = (int*)d_ws;

  hipMemsetAsync(d_out, 0, (size_t)out_size * 4, stream);  // unmasked / padded positions emit 0

  const int lds_bytes = 16384 + 131072;  // hlin (16KB) + wlds (128KB) = 144KB dynamic LDS
  hipFuncSetAttribute((const void*)k_rec, hipFuncAttributeMaxDynamicSharedMemorySize, lds_bytes);

  k_prep<<<1, 512, 0, stream>>>(mask, wsi);
  k_build<<<512, 256, 0, stream>>>(mask, wsi);
  k_wcvt<<<384, 256, 0, stream>>>(Wih, Whh, wsi);
  k_gemm<<<dim3(1024, 6), 256, 0, stream>>>(x, bih, bhh, wsi);
  k_rec<<<32, 512, lds_bytes, stream>>>(bhh, h0, wsi, out);
}